// Round 2
// baseline (699.070 us; speedup 1.0000x reference)
//
#include <hip/hip_runtime.h>
#include <math.h>

#define D_ 96
#define L_ 4096
#define K_ 8
#define N_ 16
#define R_ 6
#define CDBL 38   // R + 2N
#define DL_ (D_ * L_)

__device__ __forceinline__ float softplusf(float x) {
    return (x > 20.f) ? x : log1pf(__expf(x));
}

// source index within one channel's [64][64] image for direction k, flat pos l
__device__ __forceinline__ int src_index(int k, int l) {
    int h = l & 63, w = l >> 6;
    int lp = 4095 - l;
    int hp = lp & 63, wp = lp >> 6;
    switch (k) {
    case 0: return l;
    case 1: return (h << 6) + w;
    case 2: return lp;
    case 3: return (hp << 6) + wp;
    case 4: return (h << 6) + ((h + w) & 63);
    case 5: return (h << 6) + ((w - h) & 63);
    case 6: return (hp << 6) + ((hp + wp) & 63);
    default: return (hp << 6) + ((wp - hp) & 63);
    }
}

// ---------------- K_A: x_dbl = wproj @ cross_scan(x), gathers x inline ----------
// grid 512 = 8 k * 64 l-tiles of 64; block 256
__global__ __launch_bounds__(256) void k_xdbl(const float* __restrict__ x,
                                              const float* __restrict__ wproj,
                                              float* __restrict__ xdbl) {
    __shared__ float tile[64][100];     // [li][d], stride 100 -> b128 reads conflict-free
    __shared__ float wlds[40 * D_];     // padded to 40 rows, rows 38/39 zero
    int bid = blockIdx.x;
    int swz = (bid & 7) * 64 + (bid >> 3);   // XCD swizzle: each XCD owns one k
    int k = swz >> 6;
    int l0 = (swz & 63) * 64;

    for (int e = threadIdx.x; e < 40 * D_; e += 256)
        wlds[e] = (e < CDBL * D_) ? wproj[k * CDBL * D_ + e] : 0.f;
    for (int e = threadIdx.x; e < D_ * 64; e += 256) {
        int d = e >> 6, li = e & 63;
        tile[li][d] = x[d * L_ + src_index(k, l0 + li)];
    }
    __syncthreads();

    int lt = threadIdx.x & 63;
    int cg = threadIdx.x >> 6;          // 0..3
    float acc[10];
    #pragma unroll
    for (int j = 0; j < 10; ++j) acc[j] = 0.f;
    for (int d4 = 0; d4 < D_; d4 += 4) {
        float4 tv = *(const float4*)&tile[lt][d4];
        #pragma unroll
        for (int j = 0; j < 10; ++j) {
            int c = cg + 4 * j;
            float4 wv = *(const float4*)&wlds[c * D_ + d4];
            acc[j] = fmaf(tv.x, wv.x, acc[j]);
            acc[j] = fmaf(tv.y, wv.y, acc[j]);
            acc[j] = fmaf(tv.z, wv.z, acc[j]);
            acc[j] = fmaf(tv.w, wv.w, acc[j]);
        }
    }
    #pragma unroll
    for (int j = 0; j < 10; ++j) {
        int c = cg + 4 * j;
        if (c < CDBL) xdbl[(k * CDBL + c) * L_ + l0 + lt] = acc[j];
    }
}

// ---------------- K_B: fused delta + selective scan ----------------
// grid 256 (XCD-swizzled), block 768 = 3 chains (same k, adjacent d) x 256 threads.
// Per chain: thread t owns l in [16t,16t+16). Phase A: local scan + C*bb part of y.
// Phase B: 64-lane scan of 16 (a,b) pairs via DPP (VALU). Phase C: cross-wave carry.
// Phase D: y += C*aa*h0 (exp-only recompute).

#if __has_builtin(__builtin_amdgcn_update_dpp)
#define HAVE_DPP 1
template<int CTRL, int RM>
__device__ __forceinline__ float updpp(float oldv, float src) {
    int r = __builtin_amdgcn_update_dpp(__builtin_bit_cast(int, oldv),
                                        __builtin_bit_cast(int, src),
                                        CTRL, RM, 0xF, false);
    return __builtin_bit_cast(float, r);
}
#else
#define HAVE_DPP 0
#endif

__global__ __launch_bounds__(768) void k_scan(const float* __restrict__ xdbl,
                                              const float* __restrict__ dtw,
                                              const float* __restrict__ dtb,
                                              const float* __restrict__ alogs,
                                              const float* __restrict__ dsv_,
                                              const float* __restrict__ x,
                                              float* __restrict__ ys) {
    int bid = blockIdx.x;
    int swz = (bid & 7) * 32 + (bid >> 3);   // 256 blocks, k-per-XCD locality
    int kd0 = swz * 3;
    int k = swz >> 5;                        // = kd0/96 (3 chains never straddle k)
    int g = threadIdx.x >> 8;                // chain 0..2
    int t = threadIdx.x & 255;
    int kd = kd0 + g;
    int d = kd - k * D_;
    int lane = t & 63, wv = t >> 6;
    int l0t = t * 16;

    __shared__ float An_s[3][16];
    __shared__ float agg_a[3][4][16], agg_b[3][4][16];
    if (threadIdx.x < 48) {
        int g2 = threadIdx.x >> 4, n = threadIdx.x & 15;
        An_s[g2][n] = -expf(alogs[(kd0 + g2) * N_ + n]);
    }

    // ---- delta (fused) ----
    const float* xr = xdbl + k * CDBL * L_;
    float wr[6];
    #pragma unroll
    for (int r = 0; r < R_; ++r) wr[r] = dtw[kd * R_ + r];
    float bias = dtb[kd];
    float d16[16], u16[16], y16[16];
    #pragma unroll
    for (int i4 = 0; i4 < 4; ++i4) {
        float4 r0 = *(const float4*)(xr + 0 * L_ + l0t + i4 * 4);
        float4 r1 = *(const float4*)(xr + 1 * L_ + l0t + i4 * 4);
        float4 r2 = *(const float4*)(xr + 2 * L_ + l0t + i4 * 4);
        float4 r3 = *(const float4*)(xr + 3 * L_ + l0t + i4 * 4);
        float4 r4 = *(const float4*)(xr + 4 * L_ + l0t + i4 * 4);
        float4 r5 = *(const float4*)(xr + 5 * L_ + l0t + i4 * 4);
        float sx = fmaf(wr[0], r0.x, bias); sx = fmaf(wr[1], r1.x, sx); sx = fmaf(wr[2], r2.x, sx);
        sx = fmaf(wr[3], r3.x, sx); sx = fmaf(wr[4], r4.x, sx); sx = fmaf(wr[5], r5.x, sx);
        float sy = fmaf(wr[0], r0.y, bias); sy = fmaf(wr[1], r1.y, sy); sy = fmaf(wr[2], r2.y, sy);
        sy = fmaf(wr[3], r3.y, sy); sy = fmaf(wr[4], r4.y, sy); sy = fmaf(wr[5], r5.y, sy);
        float sz = fmaf(wr[0], r0.z, bias); sz = fmaf(wr[1], r1.z, sz); sz = fmaf(wr[2], r2.z, sz);
        sz = fmaf(wr[3], r3.z, sz); sz = fmaf(wr[4], r4.z, sz); sz = fmaf(wr[5], r5.z, sz);
        float sw = fmaf(wr[0], r0.w, bias); sw = fmaf(wr[1], r1.w, sw); sw = fmaf(wr[2], r2.w, sw);
        sw = fmaf(wr[3], r3.w, sw); sw = fmaf(wr[4], r4.w, sw); sw = fmaf(wr[5], r5.w, sw);
        d16[i4 * 4 + 0] = softplusf(sx);
        d16[i4 * 4 + 1] = softplusf(sy);
        d16[i4 * 4 + 2] = softplusf(sz);
        d16[i4 * 4 + 3] = softplusf(sw);
    }
    // ---- u gather from x ----
    const float* xd = x + d * L_;
    #pragma unroll
    for (int i = 0; i < 16; ++i) u16[i] = xd[src_index(k, l0t + i)];
    #pragma unroll
    for (int i = 0; i < 16; ++i) y16[i] = 0.f;

    __syncthreads();   // An_s ready

    const float* Bb = xdbl + (k * CDBL + R_) * L_ + l0t;
    const float* Cb = Bb + N_ * L_;
    float A16[16], B16[16];

    // ---- Phase A: local scan + bb-part of y ----
    #pragma unroll
    for (int n = 0; n < N_; ++n) {
        float An = An_s[g][n];
        float Bv[16], Cv[16];
        #pragma unroll
        for (int q = 0; q < 4; ++q) {
            *(float4*)&Bv[q * 4] = *(const float4*)(Bb + n * L_ + q * 4);
            *(float4*)&Cv[q * 4] = *(const float4*)(Cb + n * L_ + q * 4);
        }
        float ra = 1.f, rb = 0.f;
        #pragma unroll
        for (int i = 0; i < 16; ++i) {
            float a = __expf(d16[i] * An);
            float b = d16[i] * Bv[i] * u16[i];
            rb = fmaf(a, rb, b);
            ra *= a;
            y16[i] = fmaf(Cv[i], rb, y16[i]);
        }
        A16[n] = ra; B16[n] = rb;
    }

    // ---- Phase B: 64-lane inclusive scan of 16 (a,b) pairs ----
#if HAVE_DPP
#define SCAN_STAGE(CTRL, RM)                                        \
    _Pragma("unroll")                                               \
    for (int n = 0; n < N_; ++n) {                                  \
        float pa = updpp<CTRL, RM>(1.f, A16[n]);                    \
        float pb = updpp<CTRL, RM>(0.f, B16[n]);                    \
        B16[n] = fmaf(A16[n], pb, B16[n]);                          \
        A16[n] *= pa;                                               \
    }
    SCAN_STAGE(0x111, 0xF)   // row_shr:1
    SCAN_STAGE(0x112, 0xF)   // row_shr:2
    SCAN_STAGE(0x114, 0xF)   // row_shr:4
    SCAN_STAGE(0x118, 0xF)   // row_shr:8
    SCAN_STAGE(0x142, 0xA)   // row_bcast:15 -> rows 1,3
    SCAN_STAGE(0x143, 0xC)   // row_bcast:31 -> rows 2,3
#undef SCAN_STAGE
#else
    #pragma unroll
    for (int off = 1; off < 64; off <<= 1) {
        #pragma unroll
        for (int n = 0; n < N_; ++n) {
            float pa = __shfl_up(A16[n], off);
            float pb = __shfl_up(B16[n], off);
            if (lane >= off) { B16[n] = fmaf(A16[n], pb, B16[n]); A16[n] *= pa; }
        }
    }
#endif

    // exclusive prefix per lane + wave aggregates
    #pragma unroll
    for (int n = 0; n < N_; ++n) {
        float ia = A16[n], ib = B16[n];
        float ea = __shfl_up(ia, 1);
        float eb = __shfl_up(ib, 1);
        if (lane == 0) { ea = 1.f; eb = 0.f; }
        if (lane == 63) { agg_a[g][wv][n] = ia; agg_b[g][wv][n] = ib; }
        A16[n] = ea; B16[n] = eb;
    }
    __syncthreads();

    // ---- Phase C: cross-wave carry -> h0 per (thread, n) ----
    #pragma unroll
    for (int n = 0; n < N_; ++n) {
        float cb = 0.f;
        for (int w2 = 0; w2 < wv; ++w2)
            cb = fmaf(agg_a[g][w2][n], cb, agg_b[g][w2][n]);
        A16[n] = fmaf(A16[n], cb, B16[n]);   // h entering this thread's segment
    }

    // ---- Phase D: y += C * aa * h0 (exp-only recompute) ----
    #pragma unroll
    for (int n = 0; n < N_; ++n) {
        float An = An_s[g][n];
        float h0 = A16[n];
        float Cv[16];
        #pragma unroll
        for (int q = 0; q < 4; ++q)
            *(float4*)&Cv[q * 4] = *(const float4*)(Cb + n * L_ + q * 4);
        float aa = 1.f;
        #pragma unroll
        for (int i = 0; i < 16; ++i) {
            aa *= __expf(d16[i] * An);
            float tmp = aa * h0;
            y16[i] = fmaf(Cv[i], tmp, y16[i]);
        }
    }

    float dval = dsv_[kd];
    #pragma unroll
    for (int i = 0; i < 16; ++i) y16[i] = fmaf(dval, u16[i], y16[i]);
    float* yp = ys + kd * L_ + l0t;
    #pragma unroll
    for (int q = 0; q < 4; ++q)
        *(float4*)(yp + q * 4) = *(const float4*)&y16[q * 4];
}

// ---------------- K_C: cross_merge + LayerNorm fused ----------------
// grid 128 blocks x 32 positions; block 256
__global__ __launch_bounds__(256) void k_merge_ln(const float* __restrict__ ys,
                                                  const float* __restrict__ gamma,
                                                  const float* __restrict__ beta,
                                                  float* __restrict__ out) {
    __shared__ float sm[32][D_ + 1];
    __shared__ float mu_s[32], rs_s[32];
    int l0 = blockIdx.x * 32;
    for (int e = threadIdx.x; e < 32 * D_; e += 256) {
        int li = e & 31, d = e >> 5;
        int l = l0 + li;
        int h = l >> 6, w = l & 63;
        int i1 = (w << 6) + h;
        int i4 = (((w - h) & 63) << 6) + h;
        int i5 = (((w + h) & 63) << 6) + h;
        const float* bd = ys + d * L_;
        float v = bd[0 * DL_ + l] + bd[2 * DL_ + 4095 - l]
                + bd[1 * DL_ + i1] + bd[3 * DL_ + 4095 - i1]
                + bd[4 * DL_ + i4] + bd[6 * DL_ + 4095 - i4]
                + bd[5 * DL_ + i5] + bd[7 * DL_ + 4095 - i5];
        sm[li][d] = v;
    }
    __syncthreads();
    int li2 = threadIdx.x >> 3, sub = threadIdx.x & 7;
    float s = 0.f, sq = 0.f;
    for (int d = sub; d < D_; d += 8) {
        float v = sm[li2][d];
        s += v; sq = fmaf(v, v, sq);
    }
    s += __shfl_xor(s, 1); sq += __shfl_xor(sq, 1);
    s += __shfl_xor(s, 2); sq += __shfl_xor(sq, 2);
    s += __shfl_xor(s, 4); sq += __shfl_xor(sq, 4);
    if (sub == 0) {
        float mu = s * (1.f / 96.f);
        float var = sq * (1.f / 96.f) - mu * mu;
        mu_s[li2] = mu;
        rs_s[li2] = rsqrtf(var + 1e-5f);
    }
    __syncthreads();
    for (int e = threadIdx.x; e < 32 * D_; e += 256) {
        int li = e / D_, d = e - li * D_;
        float v = (sm[li][d] - mu_s[li]) * rs_s[li];
        out[(l0 + li) * D_ + d] = fmaf(v, gamma[d], beta[d]);
    }
}

extern "C" void kernel_launch(void* const* d_in, const int* in_sizes, int n_in,
                              void* d_out, int out_size, void* d_ws, size_t ws_size,
                              hipStream_t stream) {
    const float* x     = (const float*)d_in[0];
    const float* wproj = (const float*)d_in[1];
    const float* dtw   = (const float*)d_in[2];
    const float* dtb   = (const float*)d_in[3];
    const float* alogs = (const float*)d_in[4];
    const float* dsv   = (const float*)d_in[5];
    const float* gamma = (const float*)d_in[6];
    const float* beta  = (const float*)d_in[7];
    float* out = (float*)d_out;
    float* ws  = (float*)d_ws;

    float* xdbl = ws;                 // K*CDBL*L = 1,245,184 floats
    float* ysb  = ws + 1245184;       // K*D*L    = 3,145,728 floats

    hipLaunchKernelGGL(k_xdbl, dim3(512), dim3(256), 0, stream, x, wproj, xdbl);
    hipLaunchKernelGGL(k_scan, dim3(256), dim3(768), 0, stream,
                       xdbl, dtw, dtb, alogs, dsv, x, ysb);
    hipLaunchKernelGGL(k_merge_ln, dim3(128), dim3(256), 0, stream,
                       ysb, gamma, beta, out);
}

// Round 3
// 677.176 us; speedup vs baseline: 1.0323x; 1.0323x over previous
//
#include <hip/hip_runtime.h>
#include <math.h>

#define D_ 96
#define L_ 4096
#define K_ 8
#define N_ 16
#define R_ 6
#define CDBL 38   // R + 2N
#define DL_ (D_ * L_)

__device__ __forceinline__ float softplusf(float x) {
    return (x > 20.f) ? x : log1pf(__expf(x));
}

// source index within one channel's [64][64] image for direction k, flat pos l
__device__ __forceinline__ int src_index(int k, int l) {
    int h = l & 63, w = l >> 6;
    int lp = 4095 - l;
    int hp = lp & 63, wp = lp >> 6;
    switch (k) {
    case 0: return l;
    case 1: return (h << 6) + w;
    case 2: return lp;
    case 3: return (hp << 6) + wp;
    case 4: return (h << 6) + ((h + w) & 63);
    case 5: return (h << 6) + ((w - h) & 63);
    case 6: return (hp << 6) + ((hp + wp) & 63);
    default: return (hp << 6) + ((wp - hp) & 63);
    }
}

// ---------------- K_A: x_dbl = wproj @ cross_scan(x), gathers x inline ----------
// grid 512 = 8 k * 64 l-tiles of 64; block 256
__global__ __launch_bounds__(256) void k_xdbl(const float* __restrict__ x,
                                              const float* __restrict__ wproj,
                                              float* __restrict__ xdbl) {
    __shared__ float tile[64][100];     // [li][d], stride 100 -> b128 reads conflict-free
    __shared__ float wlds[40 * D_];     // padded to 40 rows, rows 38/39 zero
    int bid = blockIdx.x;
    int swz = (bid & 7) * 64 + (bid >> 3);   // XCD swizzle: each XCD owns one k
    int k = swz >> 6;
    int l0 = (swz & 63) * 64;

    for (int e = threadIdx.x; e < 40 * D_; e += 256)
        wlds[e] = (e < CDBL * D_) ? wproj[k * CDBL * D_ + e] : 0.f;
    for (int e = threadIdx.x; e < D_ * 64; e += 256) {
        int d = e >> 6, li = e & 63;
        tile[li][d] = x[d * L_ + src_index(k, l0 + li)];
    }
    __syncthreads();

    int lt = threadIdx.x & 63;
    int cg = threadIdx.x >> 6;          // 0..3
    float acc[10];
    #pragma unroll
    for (int j = 0; j < 10; ++j) acc[j] = 0.f;
    for (int d4 = 0; d4 < D_; d4 += 4) {
        float4 tv = *(const float4*)&tile[lt][d4];
        #pragma unroll
        for (int j = 0; j < 10; ++j) {
            int c = cg + 4 * j;
            float4 wv = *(const float4*)&wlds[c * D_ + d4];
            acc[j] = fmaf(tv.x, wv.x, acc[j]);
            acc[j] = fmaf(tv.y, wv.y, acc[j]);
            acc[j] = fmaf(tv.z, wv.z, acc[j]);
            acc[j] = fmaf(tv.w, wv.w, acc[j]);
        }
    }
    #pragma unroll
    for (int j = 0; j < 10; ++j) {
        int c = cg + 4 * j;
        if (c < CDBL) xdbl[(k * CDBL + c) * L_ + l0 + lt] = acc[j];
    }
}

// ---------------- K_B: fused delta + selective scan ----------------
// grid 768 (one (k,d) chain per block, XCD-swizzled: each XCD owns one k).
// Block 256. Thread t owns l in [16t,16t+16).
// Phase A: local scan + C*bb part of y. Phase B: 64-lane scan of 16 (a,b)
// pairs via DPP (VALU pipe, batched -> no serial shuffle latency chain).
// Phase C: cross-wave carry via LDS. Phase D: y += C*aa*h0 (exp recompute).
// __launch_bounds__(256,3): cap VGPR at ~170 so the ~130 live floats stay in
// registers (round-2 lesson: 768-thread block -> 84 VGPR cap -> 1.5GB scratch).

#if __has_builtin(__builtin_amdgcn_update_dpp)
#define HAVE_DPP 1
template<int CTRL, int RM>
__device__ __forceinline__ float updpp(float oldv, float src) {
    int r = __builtin_amdgcn_update_dpp(__builtin_bit_cast(int, oldv),
                                        __builtin_bit_cast(int, src),
                                        CTRL, RM, 0xF, false);
    return __builtin_bit_cast(float, r);
}
#else
#define HAVE_DPP 0
#endif

__global__ __launch_bounds__(256, 3) void k_scan(const float* __restrict__ xdbl,
                                                 const float* __restrict__ dtw,
                                                 const float* __restrict__ dtb,
                                                 const float* __restrict__ alogs,
                                                 const float* __restrict__ dsv_,
                                                 const float* __restrict__ x,
                                                 float* __restrict__ ys) {
    int bid = blockIdx.x;
    int k = bid & 7;                 // XCD swizzle: k == XCD id
    int d = bid >> 3;
    int kd = k * D_ + d;
    int t = threadIdx.x;
    int lane = t & 63, wv = t >> 6;
    int l0t = t * 16;

    __shared__ float An_s[16];
    __shared__ float agg_a[4][16], agg_b[4][16];
    if (t < 16) An_s[t] = -expf(alogs[kd * N_ + t]);

    // ---- delta (fused) ----
    const float* xr = xdbl + k * CDBL * L_;
    float wr[6];
    #pragma unroll
    for (int r = 0; r < R_; ++r) wr[r] = dtw[kd * R_ + r];
    float bias = dtb[kd];
    float d16[16], u16[16], y16[16];
    #pragma unroll
    for (int i4 = 0; i4 < 4; ++i4) {
        float4 r0 = *(const float4*)(xr + 0 * L_ + l0t + i4 * 4);
        float4 r1 = *(const float4*)(xr + 1 * L_ + l0t + i4 * 4);
        float4 r2 = *(const float4*)(xr + 2 * L_ + l0t + i4 * 4);
        float4 r3 = *(const float4*)(xr + 3 * L_ + l0t + i4 * 4);
        float4 r4 = *(const float4*)(xr + 4 * L_ + l0t + i4 * 4);
        float4 r5 = *(const float4*)(xr + 5 * L_ + l0t + i4 * 4);
        float sx = fmaf(wr[0], r0.x, bias); sx = fmaf(wr[1], r1.x, sx); sx = fmaf(wr[2], r2.x, sx);
        sx = fmaf(wr[3], r3.x, sx); sx = fmaf(wr[4], r4.x, sx); sx = fmaf(wr[5], r5.x, sx);
        float sy = fmaf(wr[0], r0.y, bias); sy = fmaf(wr[1], r1.y, sy); sy = fmaf(wr[2], r2.y, sy);
        sy = fmaf(wr[3], r3.y, sy); sy = fmaf(wr[4], r4.y, sy); sy = fmaf(wr[5], r5.y, sy);
        float sz = fmaf(wr[0], r0.z, bias); sz = fmaf(wr[1], r1.z, sz); sz = fmaf(wr[2], r2.z, sz);
        sz = fmaf(wr[3], r3.z, sz); sz = fmaf(wr[4], r4.z, sz); sz = fmaf(wr[5], r5.z, sz);
        float sw = fmaf(wr[0], r0.w, bias); sw = fmaf(wr[1], r1.w, sw); sw = fmaf(wr[2], r2.w, sw);
        sw = fmaf(wr[3], r3.w, sw); sw = fmaf(wr[4], r4.w, sw); sw = fmaf(wr[5], r5.w, sw);
        d16[i4 * 4 + 0] = softplusf(sx);
        d16[i4 * 4 + 1] = softplusf(sy);
        d16[i4 * 4 + 2] = softplusf(sz);
        d16[i4 * 4 + 3] = softplusf(sw);
    }
    // ---- u gather from x (x is 1.5MB -> L2-resident) ----
    const float* xd = x + d * L_;
    #pragma unroll
    for (int i = 0; i < 16; ++i) u16[i] = xd[src_index(k, l0t + i)];
    #pragma unroll
    for (int i = 0; i < 16; ++i) y16[i] = 0.f;

    __syncthreads();   // An_s ready

    const float* Bb = xdbl + (k * CDBL + R_) * L_ + l0t;
    const float* Cb = Bb + N_ * L_;
    float A16[16], B16[16];

    // ---- Phase A: local scan + bb-part of y ----
    #pragma unroll
    for (int n = 0; n < N_; ++n) {
        float An = An_s[n];
        float ra = 1.f, rb = 0.f;
        #pragma unroll
        for (int q = 0; q < 4; ++q) {
            float4 Bv = *(const float4*)(Bb + n * L_ + q * 4);
            float4 Cv = *(const float4*)(Cb + n * L_ + q * 4);
            float a, b;
            a = __expf(d16[q*4+0] * An); b = d16[q*4+0] * Bv.x * u16[q*4+0];
            rb = fmaf(a, rb, b); ra *= a; y16[q*4+0] = fmaf(Cv.x, rb, y16[q*4+0]);
            a = __expf(d16[q*4+1] * An); b = d16[q*4+1] * Bv.y * u16[q*4+1];
            rb = fmaf(a, rb, b); ra *= a; y16[q*4+1] = fmaf(Cv.y, rb, y16[q*4+1]);
            a = __expf(d16[q*4+2] * An); b = d16[q*4+2] * Bv.z * u16[q*4+2];
            rb = fmaf(a, rb, b); ra *= a; y16[q*4+2] = fmaf(Cv.z, rb, y16[q*4+2]);
            a = __expf(d16[q*4+3] * An); b = d16[q*4+3] * Bv.w * u16[q*4+3];
            rb = fmaf(a, rb, b); ra *= a; y16[q*4+3] = fmaf(Cv.w, rb, y16[q*4+3]);
        }
        A16[n] = ra; B16[n] = rb;
    }

    // ---- Phase B: 64-lane inclusive scan of 16 (a,b) pairs (batched, VALU) ----
#if HAVE_DPP
#define SCAN_STAGE(CTRL, RM)                                        \
    _Pragma("unroll")                                               \
    for (int n = 0; n < N_; ++n) {                                  \
        float pa = updpp<CTRL, RM>(1.f, A16[n]);                    \
        float pb = updpp<CTRL, RM>(0.f, B16[n]);                    \
        B16[n] = fmaf(A16[n], pb, B16[n]);                          \
        A16[n] *= pa;                                               \
    }
    SCAN_STAGE(0x111, 0xF)   // row_shr:1
    SCAN_STAGE(0x112, 0xF)   // row_shr:2
    SCAN_STAGE(0x114, 0xF)   // row_shr:4
    SCAN_STAGE(0x118, 0xF)   // row_shr:8
    SCAN_STAGE(0x142, 0xA)   // row_bcast:15 -> rows 1,3
    SCAN_STAGE(0x143, 0xC)   // row_bcast:31 -> rows 2,3
#undef SCAN_STAGE
#else
    #pragma unroll
    for (int off = 1; off < 64; off <<= 1) {
        #pragma unroll
        for (int n = 0; n < N_; ++n) {
            float pa = __shfl_up(A16[n], off);
            float pb = __shfl_up(B16[n], off);
            if (lane >= off) { B16[n] = fmaf(A16[n], pb, B16[n]); A16[n] *= pa; }
        }
    }
#endif

    // exclusive prefix per lane + wave aggregates
    #pragma unroll
    for (int n = 0; n < N_; ++n) {
        float ia = A16[n], ib = B16[n];
        float ea = __shfl_up(ia, 1);
        float eb = __shfl_up(ib, 1);
        if (lane == 0) { ea = 1.f; eb = 0.f; }
        if (lane == 63) { agg_a[wv][n] = ia; agg_b[wv][n] = ib; }
        A16[n] = ea; B16[n] = eb;
    }
    __syncthreads();

    // ---- Phase C: cross-wave carry -> h0 per (thread, n) ----
    #pragma unroll
    for (int n = 0; n < N_; ++n) {
        float cb = 0.f;
        for (int w2 = 0; w2 < wv; ++w2)
            cb = fmaf(agg_a[w2][n], cb, agg_b[w2][n]);
        A16[n] = fmaf(A16[n], cb, B16[n]);   // h entering this thread's segment
    }

    // ---- Phase D: y += C * aa * h0 (exp-only recompute) ----
    #pragma unroll
    for (int n = 0; n < N_; ++n) {
        float An = An_s[n];
        float h0 = A16[n];
        float aa = 1.f;
        #pragma unroll
        for (int q = 0; q < 4; ++q) {
            float4 Cv = *(const float4*)(Cb + n * L_ + q * 4);
            aa *= __expf(d16[q*4+0] * An); y16[q*4+0] = fmaf(Cv.x * aa, h0, y16[q*4+0]);
            aa *= __expf(d16[q*4+1] * An); y16[q*4+1] = fmaf(Cv.y * aa, h0, y16[q*4+1]);
            aa *= __expf(d16[q*4+2] * An); y16[q*4+2] = fmaf(Cv.z * aa, h0, y16[q*4+2]);
            aa *= __expf(d16[q*4+3] * An); y16[q*4+3] = fmaf(Cv.w * aa, h0, y16[q*4+3]);
        }
    }

    float dval = dsv_[kd];
    #pragma unroll
    for (int i = 0; i < 16; ++i) y16[i] = fmaf(dval, u16[i], y16[i]);
    float* yp = ys + kd * L_ + l0t;
    #pragma unroll
    for (int q = 0; q < 4; ++q)
        *(float4*)(yp + q * 4) = *(const float4*)&y16[q * 4];
}

// ---------------- K_C: cross_merge + LayerNorm fused ----------------
// grid 128 blocks x 32 positions; block 256
__global__ __launch_bounds__(256) void k_merge_ln(const float* __restrict__ ys,
                                                  const float* __restrict__ gamma,
                                                  const float* __restrict__ beta,
                                                  float* __restrict__ out) {
    __shared__ float sm[32][D_ + 1];
    __shared__ float mu_s[32], rs_s[32];
    int l0 = blockIdx.x * 32;
    for (int e = threadIdx.x; e < 32 * D_; e += 256) {
        int li = e & 31, d = e >> 5;
        int l = l0 + li;
        int h = l >> 6, w = l & 63;
        int i1 = (w << 6) + h;
        int i4 = (((w - h) & 63) << 6) + h;
        int i5 = (((w + h) & 63) << 6) + h;
        const float* bd = ys + d * L_;
        float v = bd[0 * DL_ + l] + bd[2 * DL_ + 4095 - l]
                + bd[1 * DL_ + i1] + bd[3 * DL_ + 4095 - i1]
                + bd[4 * DL_ + i4] + bd[6 * DL_ + 4095 - i4]
                + bd[5 * DL_ + i5] + bd[7 * DL_ + 4095 - i5];
        sm[li][d] = v;
    }
    __syncthreads();
    int li2 = threadIdx.x >> 3, sub = threadIdx.x & 7;
    float s = 0.f, sq = 0.f;
    for (int d = sub; d < D_; d += 8) {
        float v = sm[li2][d];
        s += v; sq = fmaf(v, v, sq);
    }
    s += __shfl_xor(s, 1); sq += __shfl_xor(sq, 1);
    s += __shfl_xor(s, 2); sq += __shfl_xor(sq, 2);
    s += __shfl_xor(s, 4); sq += __shfl_xor(sq, 4);
    if (sub == 0) {
        float mu = s * (1.f / 96.f);
        float var = sq * (1.f / 96.f) - mu * mu;
        mu_s[li2] = mu;
        rs_s[li2] = rsqrtf(var + 1e-5f);
    }
    __syncthreads();
    for (int e = threadIdx.x; e < 32 * D_; e += 256) {
        int li = e / D_, d = e - li * D_;
        float v = (sm[li][d] - mu_s[li]) * rs_s[li];
        out[(l0 + li) * D_ + d] = fmaf(v, gamma[d], beta[d]);
    }
}

extern "C" void kernel_launch(void* const* d_in, const int* in_sizes, int n_in,
                              void* d_out, int out_size, void* d_ws, size_t ws_size,
                              hipStream_t stream) {
    const float* x     = (const float*)d_in[0];
    const float* wproj = (const float*)d_in[1];
    const float* dtw   = (const float*)d_in[2];
    const float* dtb   = (const float*)d_in[3];
    const float* alogs = (const float*)d_in[4];
    const float* dsv   = (const float*)d_in[5];
    const float* gamma = (const float*)d_in[6];
    const float* beta  = (const float*)d_in[7];
    float* out = (float*)d_out;
    float* ws  = (float*)d_ws;

    float* xdbl = ws;                 // K*CDBL*L = 1,245,184 floats
    float* ysb  = ws + 1245184;       // K*D*L    = 3,145,728 floats

    hipLaunchKernelGGL(k_xdbl, dim3(512), dim3(256), 0, stream, x, wproj, xdbl);
    hipLaunchKernelGGL(k_scan, dim3(768), dim3(256), 0, stream,
                       xdbl, dtw, dtb, alogs, dsv, x, ysb);
    hipLaunchKernelGGL(k_merge_ln, dim3(128), dim3(256), 0, stream,
                       ysb, gamma, beta, out);
}